// Round 2
// baseline (435.413 us; speedup 1.0000x reference)
//
#include <hip/hip_runtime.h>
#include <hip/hip_bf16.h>

typedef __attribute__((ext_vector_type(8))) short short8;
typedef __attribute__((ext_vector_type(4))) float floatx4;
typedef unsigned short u16;

#define NB 32
#define NN 1536
#define NM 80
#define NH 8
#define NC 64
#define NINNER 512
#define NQD 320
#define NKD 768

__device__ __forceinline__ float bf2f(u16 u) {
    union { unsigned i; float f; } x; x.i = ((unsigned)u) << 16; return x.f;
}
__device__ __forceinline__ u16 f2bf(float f) {
    unsigned u = __float_as_uint(f);
    unsigned r = (u + 0x7FFFu + ((u >> 16) & 1u)) >> 16;  // RNE
    return (u16)r;
}
__device__ __forceinline__ short8 cvt8(const float* __restrict__ p) {
    float4 a = ((const float4*)p)[0];
    float4 b = ((const float4*)p)[1];
    short8 r;
    r[0] = (short)f2bf(a.x); r[1] = (short)f2bf(a.y);
    r[2] = (short)f2bf(a.z); r[3] = (short)f2bf(a.w);
    r[4] = (short)f2bf(b.x); r[5] = (short)f2bf(b.y);
    r[6] = (short)f2bf(b.z); r[7] = (short)f2bf(b.w);
    return r;
}

// ---------------------------------------------------------------------------
// Input dtype detect: bf16 N(0,1) data never has exponent field >= 0xA0
// (|v| >= 2^33); f32 data read as u16 has random mantissa halves at even
// indices -> ~37% of entries trip. flag=1 means inputs are f32.
// ---------------------------------------------------------------------------
__global__ __launch_bounds__(256) void detect_dtype(const u16* __restrict__ x,
                                                    int* __restrict__ flag) {
    __shared__ int cnt;
    if (threadIdx.x == 0) cnt = 0;
    __syncthreads();
    int c = 0;
    for (int i = threadIdx.x; i < 8192; i += 256) {
        unsigned e = (x[i] >> 7) & 0xFF;
        if (e >= 0xA0) c++;
    }
    atomicAdd(&cnt, c);
    __syncthreads();
    if (threadIdx.x == 0) *flag = (cnt > 64) ? 1 : 0;
}

// ---------------------------------------------------------------------------
// Mask prep: detect the storage dtype of the bool mask at runtime from byte
// patterns, then write f32 additive bias (0 or -FLT_MAX) per (b,m).
// ---------------------------------------------------------------------------
__global__ __launch_bounds__(256) void mask_prep(const unsigned char* __restrict__ raw,
                                                 float* __restrict__ maskbias) {
    __shared__ int c_bf, c_f32, c_u8;
    if (threadIdx.x == 0) { c_bf = 0; c_f32 = 0; c_u8 = 0; }
    __syncthreads();
    for (int i = threadIdx.x; i < NB * NM; i += 256) {
        unsigned char v = raw[i];
        if (v == 0x3F && (i & 3) == 1) atomicAdd(&c_bf, 1);
        if (v == 0x3F && (i & 3) == 3) atomicAdd(&c_f32, 1);
        if (v != 0 && (i & 3) != 0) atomicAdd(&c_u8, 1);
    }
    __syncthreads();
    int md;
    if (c_bf > 0) md = 2;        // bf16
    else if (c_f32 > 0) md = 3;  // f32
    else if (c_u8 > 0) md = 1;   // uint8 bool
    else md = 0;                 // int32
    for (int i = threadIdx.x; i < NB * NM; i += 256) {
        bool on;
        if (md == 2) on = ((const u16*)raw)[i] != 0;
        else if (md == 3) on = ((const float*)raw)[i] != 0.0f;
        else if (md == 1) on = raw[i] != 0;
        else on = ((const int*)raw)[i] != 0;
        maskbias[i] = on ? 0.0f : -3.4028234663852886e38f;
    }
}

// ---------------------------------------------------------------------------
// Generic bf16 MFMA GEMM: C[M x N] = A[M x K] @ B[N x K]^T (+bias).
// A_DYN/B_DYN/OUT_DYN: that pointer's dtype follows *flag (1=f32, 0=bf16);
// false means always-bf16 (internal scratch). 64x64 tile, 4 waves.
// ---------------------------------------------------------------------------
template <bool A_DYN, bool B_DYN, bool OUT_DYN, bool BIAS>
__global__ __launch_bounds__(256) void gemm_bt(const void* __restrict__ A,
                                               const void* __restrict__ Bm,
                                               const void* __restrict__ bias,
                                               void* __restrict__ C,
                                               int Ncols, int K,
                                               const int* __restrict__ flag) {
    __shared__ __align__(16) u16 As[64][40];
    __shared__ __align__(16) u16 Bs[64][40];
    const int f = *flag;
    const bool af = A_DYN && f, bfl = B_DYN && f, of = OUT_DYN && f;
    const int bn0 = blockIdx.x * 64;
    const int bm0 = blockIdx.y * 64;
    const int tid = threadIdx.x;
    const int wave = tid >> 6, lane = tid & 63;
    const int l16 = lane & 15, quad = lane >> 4;

    floatx4 acc[4];
#pragma unroll
    for (int i = 0; i < 4; ++i) acc[i] = (floatx4)0.0f;

    const int srow = tid >> 2, scol = (tid & 3) * 8;
    const size_t aoff = (size_t)(bm0 + srow) * K + scol;
    const size_t boff = (size_t)(bn0 + srow) * K + scol;

    for (int kk = 0; kk < K; kk += 32) {
        short8 av, bv;
        if (af) av = cvt8((const float*)A + aoff + kk);
        else    av = *(const short8*)((const u16*)A + aoff + kk);
        if (bfl) bv = cvt8((const float*)Bm + boff + kk);
        else     bv = *(const short8*)((const u16*)Bm + boff + kk);
        *(short8*)&As[srow][scol] = av;
        *(short8*)&Bs[srow][scol] = bv;
        __syncthreads();
        short8 a = *(const short8*)&As[16 * wave + l16][quad * 8];
#pragma unroll
        for (int nt = 0; nt < 4; ++nt) {
            short8 b = *(const short8*)&Bs[nt * 16 + l16][quad * 8];
            acc[nt] = __builtin_amdgcn_mfma_f32_16x16x32_bf16(a, b, acc[nt], 0, 0, 0);
        }
        __syncthreads();
    }

#pragma unroll
    for (int nt = 0; nt < 4; ++nt) {
        int col = bn0 + nt * 16 + l16;
        float bvadd = 0.0f;
        if (BIAS) bvadd = f ? ((const float*)bias)[col] : bf2f(((const u16*)bias)[col]);
#pragma unroll
        for (int r = 0; r < 4; ++r) {
            int row = bm0 + 16 * wave + quad * 4 + r;
            float val = acc[nt][r] + bvadd;
            if (of) ((float*)C)[(size_t)row * Ncols + col] = val;
            else    ((u16*)C)[(size_t)row * Ncols + col] = f2bf(val);
        }
    }
}

// ---------------------------------------------------------------------------
// V transpose into (b,h,c,m) with K padded 80->96 (zeros). Internal bf16.
// ---------------------------------------------------------------------------
__global__ __launch_bounds__(256) void transpose_v(const u16* __restrict__ v,
                                                   u16* __restrict__ vT) {
    int b = blockIdx.x >> 3, h = blockIdx.x & 7;
    const u16* src = v + (size_t)b * NM * NINNER + h * NC;
    u16* o = vT + (size_t)(b * NH + h) * NC * 96;
    for (int idx = threadIdx.x; idx < NM * NC; idx += 256) {
        int m = idx >> 6, c = idx & 63;
        o[c * 96 + m] = src[(size_t)m * NINNER + c];
    }
    for (int idx = threadIdx.x; idx < NC * 16; idx += 256) {
        int c = idx >> 4, m = 80 + (idx & 15);
        o[c * 96 + m] = 0;
    }
}

// ---------------------------------------------------------------------------
// Fused attention per block (b, h, 64 Q-rows): sim = q k^T * scale
// (+mask fill, +5*box, +5*road), row softmax over M=80, out = attn @ v.
// box/road dtype follows *flag; q/k/vT/attno are internal bf16.
// ---------------------------------------------------------------------------
__global__ __launch_bounds__(256) void attn_kernel(const u16* __restrict__ q,
                                                   const u16* __restrict__ k,
                                                   const u16* __restrict__ vT,
                                                   const float* __restrict__ maskbias,
                                                   const void* __restrict__ box,
                                                   const void* __restrict__ road,
                                                   u16* __restrict__ attno,
                                                   const int* __restrict__ flag) {
    const int f = *flag;
    const int n0 = blockIdx.x * 64;
    const int h = blockIdx.y;
    const int b = blockIdx.z;
    const int tid = threadIdx.x;
    const int wave = tid >> 6, lane = tid & 63;
    const int l16 = lane & 15, quad = lane >> 4;

    __shared__ __align__(16) u16 p_lds[64][104];

    floatx4 s[5];
#pragma unroll
    for (int i = 0; i < 5; ++i) s[i] = (floatx4)0.0f;
    const size_t qrow = (size_t)(b * NN + n0 + 16 * wave + l16) * NINNER + h * NC;
#pragma unroll
    for (int kk = 0; kk < NC; kk += 32) {
        short8 a = *(const short8*)(q + qrow + kk + quad * 8);
#pragma unroll
        for (int mt = 0; mt < 5; ++mt) {
            short8 bf = *(const short8*)(k + (size_t)(b * NM + mt * 16 + l16) * NINNER + h * NC + kk + quad * 8);
            s[mt] = __builtin_amdgcn_mfma_f32_16x16x32_bf16(a, bf, s[mt], 0, 0, 0);
        }
    }

    float sv[5][4];
#pragma unroll
    for (int r = 0; r < 4; ++r) {
        int n = n0 + 16 * wave + quad * 4 + r;
        size_t ridx = (size_t)b * NN + n;
        float roadv = 5.0f * (f ? ((const float*)road)[ridx] : bf2f(((const u16*)road)[ridx]));
#pragma unroll
        for (int mt = 0; mt < 5; ++mt) {
            int m = mt * 16 + l16;
            size_t bidx = ((size_t)b * NN + n) * NM + m;
            float boxv = 5.0f * (f ? ((const float*)box)[bidx] : bf2f(((const u16*)box)[bidx]));
            sv[mt][r] = s[mt][r] * 0.125f + maskbias[b * NM + m] + boxv + roadv;
        }
    }

    float rowsum[4];
#pragma unroll
    for (int r = 0; r < 4; ++r) {
        float mx = sv[0][r];
#pragma unroll
        for (int mt = 1; mt < 5; ++mt) mx = fmaxf(mx, sv[mt][r]);
#pragma unroll
        for (int off = 1; off < 16; off <<= 1) mx = fmaxf(mx, __shfl_xor(mx, off, 16));
        float sum = 0.0f;
#pragma unroll
        for (int mt = 0; mt < 5; ++mt) {
            float p = __expf(sv[mt][r] - mx);
            sv[mt][r] = p;
            sum += p;
        }
#pragma unroll
        for (int off = 1; off < 16; off <<= 1) sum += __shfl_xor(sum, off, 16);
        rowsum[r] = sum;
    }

#pragma unroll
    for (int r = 0; r < 4; ++r) {
        int lr = 16 * wave + quad * 4 + r;
#pragma unroll
        for (int mt = 0; mt < 5; ++mt) p_lds[lr][mt * 16 + l16] = f2bf(sv[mt][r]);
        p_lds[lr][80 + l16] = 0;
    }
    __syncthreads();

    floatx4 o[4];
#pragma unroll
    for (int i = 0; i < 4; ++i) o[i] = (floatx4)0.0f;
    const u16* vbase = vT + (size_t)(b * NH + h) * NC * 96;
#pragma unroll
    for (int kk = 0; kk < 96; kk += 32) {
        short8 a = *(const short8*)&p_lds[16 * wave + l16][kk + quad * 8];
#pragma unroll
        for (int nt = 0; nt < 4; ++nt) {
            short8 bf = *(const short8*)(vbase + (size_t)(nt * 16 + l16) * 96 + kk + quad * 8);
            o[nt] = __builtin_amdgcn_mfma_f32_16x16x32_bf16(a, bf, o[nt], 0, 0, 0);
        }
    }

#pragma unroll
    for (int nt = 0; nt < 4; ++nt) {
#pragma unroll
        for (int r = 0; r < 4; ++r) {
            int n = n0 + 16 * wave + quad * 4 + r;
            float inv = 1.0f / rowsum[r];
            attno[((size_t)b * NN + n) * NINNER + h * NC + nt * 16 + l16] = f2bf(o[nt][r] * inv);
        }
    }
}

extern "C" void kernel_launch(void* const* d_in, const int* in_sizes, int n_in,
                              void* d_out, int out_size, void* d_ws, size_t ws_size,
                              hipStream_t stream) {
    (void)in_sizes; (void)n_in; (void)out_size; (void)ws_size;
    const void* x    = d_in[0];
    const void* key  = d_in[1];
    const void* val  = d_in[2];
    const unsigned char* mask = (const unsigned char*)d_in[3];
    const void* box  = d_in[4];
    const void* road = d_in[5];
    const void* Wq   = d_in[6];
    const void* Wk   = d_in[7];
    const void* Wv   = d_in[8];
    const void* Wo   = d_in[9];
    const void* bo   = d_in[10];

    char* ws = (char*)d_ws;
    size_t off = 0;
    auto carve = [&](size_t bytes) {
        char* p = ws + off;
        off += (bytes + 255) & ~(size_t)255;
        return p;
    };
    int* flag  = (int*)carve(256);
    u16* q_ws  = (u16*)carve((size_t)NB * NN * NINNER * 2);   // 48 MB
    u16* k_ws  = (u16*)carve((size_t)NB * NM * NINNER * 2);   // 2.6 MB
    u16* v_ws  = (u16*)carve((size_t)NB * NM * NINNER * 2);   // 2.6 MB
    u16* vT_ws = (u16*)carve((size_t)NB * NH * NC * 96 * 2);  // 3.1 MB
    u16* ao_ws = (u16*)carve((size_t)NB * NN * NINNER * 2);   // 48 MB
    float* mb  = (float*)carve((size_t)NB * NM * 4);

    detect_dtype<<<1, 256, 0, stream>>>((const u16*)x, flag);
    mask_prep<<<1, 256, 0, stream>>>(mask, mb);
    // q = x @ Wq^T : (49152 x 320) @ (512 x 320)^T -> bf16 scratch
    gemm_bt<true, true, false, false><<<dim3(NINNER / 64, NB * NN / 64), 256, 0, stream>>>(
        x, Wq, nullptr, q_ws, NINNER, NQD, flag);
    // k = key @ Wk^T, v = value @ Wv^T : (2560 x 768) @ (512 x 768)^T
    gemm_bt<true, true, false, false><<<dim3(NINNER / 64, NB * NM / 64), 256, 0, stream>>>(
        key, Wk, nullptr, k_ws, NINNER, NKD, flag);
    gemm_bt<true, true, false, false><<<dim3(NINNER / 64, NB * NM / 64), 256, 0, stream>>>(
        val, Wv, nullptr, v_ws, NINNER, NKD, flag);
    transpose_v<<<NB * NH, 256, 0, stream>>>(v_ws, vT_ws);
    attn_kernel<<<dim3(NN / 64, NH, NB), 256, 0, stream>>>(
        q_ws, k_ws, vT_ws, mb, box, road, ao_ws, flag);
    // out = attno @ Wo^T + bo : (49152 x 512) @ (320 x 512)^T -> dtype per flag
    gemm_bt<false, true, true, true><<<dim3(NQD / 64, NB * NN / 64), 256, 0, stream>>>(
        ao_ws, Wo, bo, d_out, NQD, NINNER, flag);
}

// Round 3
// 349.562 us; speedup vs baseline: 1.2456x; 1.2456x over previous
//
#include <hip/hip_runtime.h>
#include <hip/hip_bf16.h>

typedef __attribute__((ext_vector_type(8))) short short8;
typedef __attribute__((ext_vector_type(4))) float floatx4;
typedef unsigned short u16;

#define NB 32
#define NN 1536
#define NM 80
#define NH 8
#define NC 64
#define NINNER 512
#define NQD 320
#define NKD 768

__device__ __forceinline__ float bf2f(u16 u) {
    union { unsigned i; float f; } x; x.i = ((unsigned)u) << 16; return x.f;
}
__device__ __forceinline__ u16 f2bf(float f) {
    unsigned u = __float_as_uint(f);
    unsigned r = (u + 0x7FFFu + ((u >> 16) & 1u)) >> 16;  // RNE
    return (u16)r;
}
__device__ __forceinline__ short8 cvt8(const float* __restrict__ p) {
    float4 a = ((const float4*)p)[0];
    float4 b = ((const float4*)p)[1];
    short8 r;
    r[0] = (short)f2bf(a.x); r[1] = (short)f2bf(a.y);
    r[2] = (short)f2bf(a.z); r[3] = (short)f2bf(a.w);
    r[4] = (short)f2bf(b.x); r[5] = (short)f2bf(b.y);
    r[6] = (short)f2bf(b.z); r[7] = (short)f2bf(b.w);
    return r;
}
__device__ __forceinline__ void gload16(const u16* g, u16* l) {
    __builtin_amdgcn_global_load_lds(
        (const __attribute__((address_space(1))) unsigned int*)g,
        (__attribute__((address_space(3))) unsigned int*)l, 16, 0, 0);
}

// ---------------------------------------------------------------------------
// Input dtype detect: flag=1 means inputs are f32 (bf16 N(0,1) data never has
// exponent field >= 0xA0; f32 read as u16 trips ~37% of the time).
// ---------------------------------------------------------------------------
__global__ __launch_bounds__(256) void detect_dtype(const u16* __restrict__ x,
                                                    int* __restrict__ flag) {
    __shared__ int cnt;
    if (threadIdx.x == 0) cnt = 0;
    __syncthreads();
    int c = 0;
    for (int i = threadIdx.x; i < 8192; i += 256) {
        unsigned e = (x[i] >> 7) & 0xFF;
        if (e >= 0xA0) c++;
    }
    atomicAdd(&cnt, c);
    __syncthreads();
    if (threadIdx.x == 0) *flag = (cnt > 64) ? 1 : 0;
}

// ---------------------------------------------------------------------------
// Mask prep (self-detecting storage dtype) -> f32 additive bias per (b,m).
// ---------------------------------------------------------------------------
__global__ __launch_bounds__(256) void mask_prep(const unsigned char* __restrict__ raw,
                                                 float* __restrict__ maskbias) {
    __shared__ int c_bf, c_f32, c_u8;
    if (threadIdx.x == 0) { c_bf = 0; c_f32 = 0; c_u8 = 0; }
    __syncthreads();
    for (int i = threadIdx.x; i < NB * NM; i += 256) {
        unsigned char v = raw[i];
        if (v == 0x3F && (i & 3) == 1) atomicAdd(&c_bf, 1);
        if (v == 0x3F && (i & 3) == 3) atomicAdd(&c_f32, 1);
        if (v != 0 && (i & 3) != 0) atomicAdd(&c_u8, 1);
    }
    __syncthreads();
    int md;
    if (c_bf > 0) md = 2;
    else if (c_f32 > 0) md = 3;
    else if (c_u8 > 0) md = 1;
    else md = 0;
    for (int i = threadIdx.x; i < NB * NM; i += 256) {
        bool on;
        if (md == 2) on = ((const u16*)raw)[i] != 0;
        else if (md == 3) on = ((const float*)raw)[i] != 0.0f;
        else if (md == 1) on = raw[i] != 0;
        else on = ((const int*)raw)[i] != 0;
        maskbias[i] = on ? 0.0f : -3.4028234663852886e38f;
    }
}

// ---------------------------------------------------------------------------
// Batched f32->bf16 conversion (or u16 copy when flag=0). All segment sizes
// are exact multiples of 2048 elements (one block = 256 thr x 8 elems).
// ---------------------------------------------------------------------------
struct ConvSeg { const void* src; u16* dst; int nblk; };
struct ConvArgs { ConvSeg s[6]; };

__global__ __launch_bounds__(256) void conv_batch(ConvArgs a, const int* __restrict__ flag) {
    const int f = *flag;
    int b = blockIdx.x, seg = 0;
    while (seg < 6 && b >= a.s[seg].nblk) { b -= a.s[seg].nblk; seg++; }
    if (seg >= 6) return;
    const long idx = (long)b * 2048 + threadIdx.x * 8;
    u16* dst = a.s[seg].dst;
    if (f) *(short8*)(dst + idx) = cvt8((const float*)a.s[seg].src + idx);
    else   *(short8*)(dst + idx) = *(const short8*)((const u16*)a.s[seg].src + idx);
}

// Wo (320x512) -> padded bf16 (384x512), zero rows 320..383.  96 blocks.
__global__ __launch_bounds__(256) void conv_wo(const void* __restrict__ src,
                                               u16* __restrict__ dst,
                                               const int* __restrict__ flag) {
    const int f = *flag;
    const long idx = ((long)blockIdx.x * 256 + threadIdx.x) * 8;
    const int row = (int)(idx >> 9);
    if (row < NQD) {
        if (f) *(short8*)(dst + idx) = cvt8((const float*)src + idx);
        else   *(short8*)(dst + idx) = *(const short8*)((const u16*)src + idx);
    } else {
        *(short8*)(dst + idx) = (short8)0;
    }
}

// ---------------------------------------------------------------------------
// m97-style bf16 MFMA GEMM: C[M x Nreal] = A[M x K] @ B[Npad x K]^T (+bias).
// 128x128 tile, BK=32, 4 waves in 2x2, each owning 64x64 (4x4 MFMA tiles).
// global_load_lds width=16 with XOR-swizzled source chunks so the forced
// linear LDS layout is conflict-free on ds_read_b128 (2-way max).
// Grid: (M/128, Npad/128 [, 2 if DUAL]).
// ---------------------------------------------------------------------------
template <bool OUT_DYN, bool BIAS, bool DUAL>
__global__ __launch_bounds__(256) void gemm128(const u16* __restrict__ A,
                                               const u16* __restrict__ B,
                                               const void* __restrict__ bias,
                                               void* __restrict__ C,
                                               const u16* __restrict__ A2,
                                               const u16* __restrict__ B2,
                                               void* __restrict__ C2,
                                               int Nreal, int K,
                                               const int* __restrict__ flag) {
    __shared__ __align__(16) u16 As[128 * 32];
    __shared__ __align__(16) u16 Bs[128 * 32];
    if (DUAL && blockIdx.z) { A = A2; B = B2; C = C2; }
    const int f = *flag;
    const int tid = threadIdx.x;
    const int wave = tid >> 6, lane = tid & 63;
    const int l16 = lane & 15, quad = lane >> 4;
    const int wr = wave >> 1, wc = wave & 1;
    const int bm0 = blockIdx.x * 128, bn0 = blockIdx.y * 128;

    // staging: thread t covers LDS row r0 = t/4, chunk c0 = t%4 of each issue
    const int r0 = tid >> 2, c0 = tid & 3;
    const int sc = c0 ^ ((r0 >> 1) & 3);            // swizzled source chunk
    const u16* Ag = A + (size_t)(bm0 + r0) * K + sc * 8;
    const u16* Bg = B + (size_t)(bn0 + r0) * K + sc * 8;
    u16* AsW = As + wave * 512;                     // per-wave LDS base (1 KiB)
    u16* BsW = Bs + wave * 512;

    const int swz = (l16 >> 1) & 3;                 // read-side chunk swizzle
    floatx4 acc[4][4];
#pragma unroll
    for (int i = 0; i < 4; ++i)
#pragma unroll
        for (int n = 0; n < 4; ++n) acc[i][n] = (floatx4)0.0f;

    for (int kk = 0; kk < K; kk += 32) {
        __syncthreads();                            // prev-iter reads done (WAR)
#pragma unroll
        for (int j = 0; j < 2; ++j) {
            gload16(Ag + (size_t)(j * 64) * K + kk, AsW + j * 2048);
            gload16(Bg + (size_t)(j * 64) * K + kk, BsW + j * 2048);
        }
        __syncthreads();                            // drains vmcnt: tiles landed
        short8 af[4], bf[4];
#pragma unroll
        for (int i = 0; i < 4; ++i)
            af[i] = *(const short8*)&As[(wr * 64 + i * 16 + l16) * 32 + ((quad ^ swz) * 8)];
#pragma unroll
        for (int n = 0; n < 4; ++n)
            bf[n] = *(const short8*)&Bs[(wc * 64 + n * 16 + l16) * 32 + ((quad ^ swz) * 8)];
#pragma unroll
        for (int i = 0; i < 4; ++i)
#pragma unroll
            for (int n = 0; n < 4; ++n)
                acc[i][n] = __builtin_amdgcn_mfma_f32_16x16x32_bf16(af[i], bf[n], acc[i][n], 0, 0, 0);
    }

#pragma unroll
    for (int n = 0; n < 4; ++n) {
        const int col = bn0 + wc * 64 + n * 16 + l16;
        if (col < Nreal) {
            float badd = 0.0f;
            if (BIAS) badd = f ? ((const float*)bias)[col] : bf2f(((const u16*)bias)[col]);
#pragma unroll
            for (int i = 0; i < 4; ++i)
#pragma unroll
                for (int r = 0; r < 4; ++r) {
                    const int row = bm0 + wr * 64 + i * 16 + quad * 4 + r;
                    const float val = acc[i][n][r] + badd;
                    if (OUT_DYN && f) ((float*)C)[(size_t)row * Nreal + col] = val;
                    else              ((u16*)C)[(size_t)row * Nreal + col] = f2bf(val);
                }
        }
    }
}

// ---------------------------------------------------------------------------
// V transpose into (b,h,c,m) with K padded 80->96 (zeros). Internal bf16.
// ---------------------------------------------------------------------------
__global__ __launch_bounds__(256) void transpose_v(const u16* __restrict__ v,
                                                   u16* __restrict__ vT) {
    int b = blockIdx.x >> 3, h = blockIdx.x & 7;
    const u16* src = v + (size_t)b * NM * NINNER + h * NC;
    u16* o = vT + (size_t)(b * NH + h) * NC * 96;
    for (int idx = threadIdx.x; idx < NM * NC; idx += 256) {
        int m = idx >> 6, c = idx & 63;
        o[c * 96 + m] = src[(size_t)m * NINNER + c];
    }
    for (int idx = threadIdx.x; idx < NC * 16; idx += 256) {
        int c = idx >> 4, m = 80 + (idx & 15);
        o[c * 96 + m] = 0;
    }
}

// ---------------------------------------------------------------------------
// Fused attention per block (b, h, 64 Q-rows). box/road read per flag dtype.
// ---------------------------------------------------------------------------
__global__ __launch_bounds__(256) void attn_kernel(const u16* __restrict__ q,
                                                   const u16* __restrict__ k,
                                                   const u16* __restrict__ vT,
                                                   const float* __restrict__ maskbias,
                                                   const void* __restrict__ box,
                                                   const void* __restrict__ road,
                                                   u16* __restrict__ attno,
                                                   const int* __restrict__ flag) {
    const int f = *flag;
    const int n0 = blockIdx.x * 64;
    const int h = blockIdx.y;
    const int b = blockIdx.z;
    const int tid = threadIdx.x;
    const int wave = tid >> 6, lane = tid & 63;
    const int l16 = lane & 15, quad = lane >> 4;

    __shared__ __align__(16) u16 p_lds[64][104];

    floatx4 s[5];
#pragma unroll
    for (int i = 0; i < 5; ++i) s[i] = (floatx4)0.0f;
    const size_t qrow = (size_t)(b * NN + n0 + 16 * wave + l16) * NINNER + h * NC;
#pragma unroll
    for (int kk = 0; kk < NC; kk += 32) {
        short8 a = *(const short8*)(q + qrow + kk + quad * 8);
#pragma unroll
        for (int mt = 0; mt < 5; ++mt) {
            short8 bf = *(const short8*)(k + (size_t)(b * NM + mt * 16 + l16) * NINNER + h * NC + kk + quad * 8);
            s[mt] = __builtin_amdgcn_mfma_f32_16x16x32_bf16(a, bf, s[mt], 0, 0, 0);
        }
    }

    float sv[5][4];
#pragma unroll
    for (int r = 0; r < 4; ++r) {
        int n = n0 + 16 * wave + quad * 4 + r;
        size_t ridx = (size_t)b * NN + n;
        float roadv = 5.0f * (f ? ((const float*)road)[ridx] : bf2f(((const u16*)road)[ridx]));
#pragma unroll
        for (int mt = 0; mt < 5; ++mt) {
            int m = mt * 16 + l16;
            size_t bidx = ((size_t)b * NN + n) * NM + m;
            float boxv = 5.0f * (f ? ((const float*)box)[bidx] : bf2f(((const u16*)box)[bidx]));
            sv[mt][r] = s[mt][r] * 0.125f + maskbias[b * NM + m] + boxv + roadv;
        }
    }

    float rowsum[4];
#pragma unroll
    for (int r = 0; r < 4; ++r) {
        float mx = sv[0][r];
#pragma unroll
        for (int mt = 1; mt < 5; ++mt) mx = fmaxf(mx, sv[mt][r]);
#pragma unroll
        for (int off = 1; off < 16; off <<= 1) mx = fmaxf(mx, __shfl_xor(mx, off, 16));
        float sum = 0.0f;
#pragma unroll
        for (int mt = 0; mt < 5; ++mt) {
            float p = __expf(sv[mt][r] - mx);
            sv[mt][r] = p;
            sum += p;
        }
#pragma unroll
        for (int off = 1; off < 16; off <<= 1) sum += __shfl_xor(sum, off, 16);
        rowsum[r] = sum;
    }

#pragma unroll
    for (int r = 0; r < 4; ++r) {
        int lr = 16 * wave + quad * 4 + r;
#pragma unroll
        for (int mt = 0; mt < 5; ++mt) p_lds[lr][mt * 16 + l16] = f2bf(sv[mt][r]);
        p_lds[lr][80 + l16] = 0;
    }
    __syncthreads();

    floatx4 o[4];
#pragma unroll
    for (int i = 0; i < 4; ++i) o[i] = (floatx4)0.0f;
    const u16* vbase = vT + (size_t)(b * NH + h) * NC * 96;
#pragma unroll
    for (int kk = 0; kk < 96; kk += 32) {
        short8 a = *(const short8*)&p_lds[16 * wave + l16][kk + quad * 8];
#pragma unroll
        for (int nt = 0; nt < 4; ++nt) {
            short8 bf = *(const short8*)(vbase + (size_t)(nt * 16 + l16) * 96 + kk + quad * 8);
            o[nt] = __builtin_amdgcn_mfma_f32_16x16x32_bf16(a, bf, o[nt], 0, 0, 0);
        }
    }

#pragma unroll
    for (int nt = 0; nt < 4; ++nt) {
#pragma unroll
        for (int r = 0; r < 4; ++r) {
            int n = n0 + 16 * wave + quad * 4 + r;
            float inv = 1.0f / rowsum[r];
            attno[((size_t)b * NN + n) * NINNER + h * NC + nt * 16 + l16] = f2bf(o[nt][r] * inv);
        }
    }
}

extern "C" void kernel_launch(void* const* d_in, const int* in_sizes, int n_in,
                              void* d_out, int out_size, void* d_ws, size_t ws_size,
                              hipStream_t stream) {
    (void)in_sizes; (void)n_in; (void)out_size; (void)ws_size;
    const void* x    = d_in[0];
    const void* key  = d_in[1];
    const void* val  = d_in[2];
    const unsigned char* mask = (const unsigned char*)d_in[3];
    const void* box  = d_in[4];
    const void* road = d_in[5];
    const void* Wq   = d_in[6];
    const void* Wk   = d_in[7];
    const void* Wv   = d_in[8];
    const void* Wo   = d_in[9];
    const void* bo   = d_in[10];

    char* ws = (char*)d_ws;
    size_t off = 0;
    auto carve = [&](size_t bytes) {
        char* p = ws + off;
        off += (bytes + 255) & ~(size_t)255;
        return p;
    };
    int* flag   = (int*)carve(256);
    u16* q_ws   = (u16*)carve((size_t)NB * NN * NINNER * 2);   // 50.3 MB
    u16* k_ws   = (u16*)carve((size_t)NB * NM * NINNER * 2);   // 2.6 MB
    u16* v_ws   = (u16*)carve((size_t)NB * NM * NINNER * 2);   // 2.6 MB
    u16* vT_ws  = (u16*)carve((size_t)NB * NH * NC * 96 * 2);  // 3.1 MB
    u16* ao_ws  = (u16*)carve((size_t)NB * NN * NINNER * 2);   // 50.3 MB
    u16* x_bf   = ao_ws;  // alias: x_bf dead before attn writes ao_ws
    u16* key_bf = (u16*)carve((size_t)NB * NM * NKD * 2);      // 3.9 MB
    u16* val_bf = (u16*)carve((size_t)NB * NM * NKD * 2);      // 3.9 MB
    u16* Wq_bf  = (u16*)carve((size_t)NINNER * NQD * 2);
    u16* Wk_bf  = (u16*)carve((size_t)NINNER * NKD * 2);
    u16* Wv_bf  = (u16*)carve((size_t)NINNER * NKD * 2);
    u16* WoP_bf = (u16*)carve((size_t)384 * NINNER * 2);
    float* mb   = (float*)carve((size_t)NB * NM * 4);

    detect_dtype<<<1, 256, 0, stream>>>((const u16*)x, flag);
    mask_prep<<<1, 256, 0, stream>>>(mask, mb);

    ConvArgs ca;
    ca.s[0] = { x,     x_bf,   (int)((size_t)NB * NN * NQD / 2048) };   // 7680
    ca.s[1] = { key,   key_bf, (int)((size_t)NB * NM * NKD / 2048) };   // 960
    ca.s[2] = { val,   val_bf, (int)((size_t)NB * NM * NKD / 2048) };   // 960
    ca.s[3] = { Wq,    Wq_bf,  (int)((size_t)NINNER * NQD / 2048) };    // 80
    ca.s[4] = { Wk,    Wk_bf,  (int)((size_t)NINNER * NKD / 2048) };    // 192
    ca.s[5] = { Wv,    Wv_bf,  (int)((size_t)NINNER * NKD / 2048) };    // 192
    int totblk = 0;
    for (int i = 0; i < 6; ++i) totblk += ca.s[i].nblk;
    conv_batch<<<totblk, 256, 0, stream>>>(ca, flag);
    conv_wo<<<96, 256, 0, stream>>>(Wo, WoP_bf, flag);

    // q = x @ Wq^T : (49152 x 320) @ (512 x 320)^T -> bf16
    gemm128<false, false, false><<<dim3(NB * NN / 128, NINNER / 128), 256, 0, stream>>>(
        x_bf, Wq_bf, nullptr, q_ws, nullptr, nullptr, nullptr, NINNER, NQD, flag);
    // k/v = {key,value} @ {Wk,Wv}^T : (2560 x 768) @ (512 x 768)^T, dual
    gemm128<false, false, true><<<dim3(NB * NM / 128, NINNER / 128, 2), 256, 0, stream>>>(
        key_bf, Wk_bf, nullptr, k_ws, val_bf, Wv_bf, v_ws, NINNER, NKD, flag);
    transpose_v<<<NB * NH, 256, 0, stream>>>(v_ws, vT_ws);
    attn_kernel<<<dim3(NN / 64, NH, NB), 256, 0, stream>>>(
        q_ws, k_ws, vT_ws, mb, box, road, ao_ws, flag);
    // out = attno @ WoP^T + bo : (49152 x 512) @ (384 x 512)^T, Nreal=320
    gemm128<true, true, false><<<dim3(NB * NN / 128, 384 / 128), 256, 0, stream>>>(
        ao_ws, WoP_bf, bo, d_out, nullptr, nullptr, nullptr, NQD, NINNER, flag);
}